// Round 14
// baseline (749.551 us; speedup 1.0000x reference)
//
#include <hip/hip_runtime.h>

#define HH 320
#define WW 320
#define BB 8
static constexpr float EPS = 1e-5f;

typedef __attribute__((ext_vector_type(8))) short bf16x8;
typedef __attribute__((ext_vector_type(4))) float f32x4;

__device__ inline float bf2f(unsigned short u) {
    union { unsigned int i; float f; } v; v.i = ((unsigned int)u) << 16; return v.f;
}
__device__ inline unsigned short f2bf(float f) {
    union { float f; unsigned int i; } v; v.f = f;
    unsigned int r = v.i + 0x7fffu + ((v.i >> 16) & 1u);
    return (unsigned short)(r >> 16);
}
__device__ inline unsigned int cvtpk(float a, float b) {   // lo16=bf16(a), hi16=bf16(b)
    unsigned int r;
    asm volatile("v_cvt_pk_bf16_f32 %0, %1, %2" : "=v"(r) : "v"(a), "v"(b));
    return r;
}
__device__ inline void glds16(const void* g, void* l) {
    __builtin_amdgcn_global_load_lds(
        (const __attribute__((address_space(1))) unsigned int*)g,
        (__attribute__((address_space(3))) unsigned int*)l, 16, 0, 0);
}

// ---------------- NCHW fp32 -> NHWC bf16 (CIN=32) ----------------
__global__ __launch_bounds__(256) void prep_hwc(const float* __restrict__ in,
                                                unsigned short* __restrict__ out)
{
    __shared__ float sT[32][65];
    const int tid = threadIdx.x;
    const int x0  = blockIdx.x * 64;
    const int y   = blockIdx.y;
    const int b   = blockIdx.z;
    for (int e = tid; e < 32 * 64; e += 256) {
        int c = e >> 6, x = e & 63;
        sT[c][x] = in[(((size_t)(b * 32 + c) * HH) + y) * WW + x0 + x];
    }
    __syncthreads();
    for (int e = tid; e < 64 * 32; e += 256) {
        int x = e >> 5, c = e & 31;
        out[((((size_t)b * HH + y) * WW) + x0 + x) * 32 + c] = f2bf(sT[c][x]);
    }
}

// ------ weights OIHW fp32 -> bank-swizzled bf16 images ------
// unit i = icc*2304 + kk*256 + oc*4 + s; content j = w[oc][icc*32 + (s^swz(oc))*8 + j][kk]
__global__ __launch_bounds__(256) void wprep_swz(const float* __restrict__ w1,
                                                 const float* __restrict__ w2,
                                                 unsigned short* __restrict__ wt1,
                                                 unsigned short* __restrict__ wt2)
{
    int i = blockIdx.x * 256 + threadIdx.x;
    if (i < 2304) {
        int s = i & 3, oc = (i >> 2) & 63, kk = i >> 8;
        int icq = s ^ ((oc >> 1) & 3);
        const float* src = w1 + ((size_t)oc * 32 + icq * 8) * 9 + kk;
        unsigned short pk[8];
#pragma unroll
        for (int j = 0; j < 8; ++j) pk[j] = f2bf(src[j * 9]);
        *(bf16x8*)&wt1[(size_t)i * 8] = *(bf16x8*)pk;
    }
    if (i < 4608) {
        int icc = i / 2304, u = i - icc * 2304;
        int s = u & 3, oc = (u >> 2) & 63, kk = u >> 8;
        int icq = s ^ ((oc >> 1) & 3);
        const float* src = w2 + ((size_t)oc * 64 + icc * 32 + icq * 8) * 9 + kk;
        unsigned short pk[8];
#pragma unroll
        for (int j = 0; j < 8; ++j) pk[j] = f2bf(src[j * 9]);
        *(bf16x8*)&wt2[(size_t)i * 8] = *(bf16x8*)pk;
    }
}

// ------ fold conv1 InstanceNorm scale into conv2 weights (per batch) ------
__global__ __launch_bounds__(256) void wfold(const unsigned short* __restrict__ wt2,
                                             const float* __restrict__ b2,
                                             const float2* __restrict__ stats1,
                                             unsigned short* __restrict__ wt2b,
                                             float* __restrict__ bias2b)
{
    __shared__ float sMu[64], sR[64];
    __shared__ float sBias[256];
    const int b = blockIdx.x, tid = threadIdx.x;
    if (tid < 64) {
        float2 ms = stats1[b * 64 + tid];
        sMu[tid] = bf2f(f2bf(ms.x));     // mu_bf, consistent with staged pads
        sR[tid]  = ms.y;
    }
    __syncthreads();
    const int oc = tid & 63, rep = tid >> 6;
    float bsum = 0.f;
    for (int cs = rep * 2; cs < rep * 2 + 2; ++cs) {
        int icc = cs >> 2, s = cs & 3;
        int icq = s ^ ((oc >> 1) & 3);
        for (int kk = 0; kk < 9; ++kk) {
            size_t u = (size_t)icc * 2304 + kk * 256 + oc * 4 + s;
            bf16x8 v = *(const bf16x8*)&wt2[u * 8];
            unsigned short o8[8];
#pragma unroll
            for (int j = 0; j < 8; ++j) {
                int ic = icc * 32 + icq * 8 + j;
                unsigned short wb = f2bf(bf2f(((unsigned short*)&v)[j]) * sR[ic]);
                o8[j] = wb;
                bsum += bf2f(wb) * sMu[ic];
            }
            *(bf16x8*)&wt2b[((size_t)b * 4608 + u) * 8] = *(bf16x8*)o8;
        }
    }
    sBias[tid] = bsum;
    __syncthreads();
    if (tid < 64) {
        float t = sBias[tid] + sBias[tid + 64] + sBias[tid + 128] + sBias[tid + 192];
        bias2b[b * 64 + tid] = b2[tid] - t;
    }
}

// ---------- implicit-GEMM conv 3x3: long-burst groups, B from L2 ----------
// Block: 4 waves; supertile = 4 y-subtiles (16 rows) x 64 px x 64 oc; 800 blocks.
// Group (t,icc): ONE barrier pair around 9 taps x 16 = 144 MFMA. B-fragments
// read per-tap directly from the L2-resident weight image (no sW LDS, no slab
// barriers). sA double-buffered (2 x 25.3 KB); LDS ~53 KB -> 3 blocks/CU.
// NORM=0 (conv1): sA via glds at group top (drains free under 144 MFMA).
// NORM=1 (conv2): T14 issue-early/write-late in 2 half-chunks (<=16 regs live);
//                 sA = bf16(max(h, mu_bf)); scale folded into wt2b; pads = mu_bf.
template<int CIN, int NORM>
__global__ __launch_bounds__(256, 3) void conv_mfma(
    const unsigned short* __restrict__ in_hwc,   // [B][H][W][CIN] bf16
    const float2* __restrict__ stats_in,         // [B*64] (NORM)
    const unsigned short* __restrict__ wt,       // weight image; per-batch when NORM
    const float* __restrict__ bias,              // [64]; per-batch when NORM
    unsigned short* __restrict__ out_hwc,        // [B][H][W][64] bf16
    float2* __restrict__ partials)               // [B*100][64]
{
    constexpr int ICC = CIN / 32;
    constexpr int NG  = 4 * ICC;

    __shared__ __align__(16) unsigned short sA[2][6 * 264 * 8];   // 2 x 25344 B
    __shared__ float sRedS[256];
    __shared__ float sRedSS[256];
    __shared__ float sMaxMu[64];
    __shared__ unsigned short sMuBf[64];

    const int tid = threadIdx.x;
    const int x0  = blockIdx.x * 64;
    const int yb  = blockIdx.y * 16;
    const int b   = blockIdx.z;
    const int w   = tid >> 6;
    const int l   = tid & 63;
    const int lm  = l & 15;
    const int g   = l >> 4;

    const unsigned short* wtb = NORM ? wt + (size_t)b * 4608 * 8 : wt;
    const float* biasb        = NORM ? bias + b * 64 : bias;

    if (NORM) {
        if (tid < 64) {
            float2 ms = stats_in[b * 64 + tid];
            unsigned short mb = f2bf(ms.x);
            sMuBf[tid]  = mb;
            sMaxMu[tid] = bf2f(mb);
        }
    }

    // ---- NORM=0: glds group stage (source pre-permuted for bank swizzle) ----
    auto issueA_glds = [&](int gi2) {
        int t2 = gi2 / ICC, icc2 = gi2 % ICC;
        int y02 = yb + t2 * 4;
        unsigned short* buf = &sA[gi2 & 1][0];
        for (int r = w; r < 6; r += 4) {
            int gy = y02 + r - 1;
            unsigned short* ldsrow = buf + r * 2112;
            if ((unsigned)gy < HH) {
                const unsigned short* rowbase =
                    in_hwc + ((size_t)(b * HH + gy) * WW) * CIN + icc2 * 32;
#pragma unroll
                for (int i = 0; i < 4; ++i) {
                    int u  = 4 + i * 64 + l;
                    int x  = u >> 2;
                    int cs = (u & 3) ^ ((x >> 1) & 3);
                    glds16(rowbase + (size_t)(x0 + x - 1) * CIN + cs * 8,
                           ldsrow + (size_t)(4 + i * 64) * 8);
                }
            } else {
                for (int u2 = l; u2 < 264; u2 += 64)
                    *(bf16x8*)(ldsrow + u2 * 8) = (bf16x8){0,0,0,0,0,0,0,0};
            }
        }
        if (tid < 48) {   // px slots 0 and 65 (swizzle identity there)
            int icq = tid & 3, side = (tid >> 2) & 1, r = tid >> 3;
            int xs = side ? 65 : 0;
            int gy = y02 + r - 1, gx = x0 + xs - 1;
            bf16x8 v = (bf16x8){0,0,0,0,0,0,0,0};
            if ((unsigned)gy < HH && (unsigned)gx < WW)
                v = *(const bf16x8*)&in_hwc[(((size_t)(b * HH + gy) * WW) + gx) * CIN + icc2 * 32 + icq * 8];
            *(bf16x8*)&buf[(r * 264 + xs * 4 + icq) * 8] = v;
        }
    };

    // ---- NORM=1: reg-staged chunks (issue-early / transform+write-late) ----
    bf16x8 ld[7];
    auto issue_chunk = [&](int gi2, int k) {
        int t2 = gi2 / ICC, icc2 = gi2 % ICC;
        int y02 = yb + t2 * 4;
        int e = tid + k * 256;
        if (e < 1584) {
            int r = e / 264, rem = e - r * 264;
            int x = rem >> 2, icq = rem & 3;
            int gy = y02 + r - 1, gx = x0 + x - 1;
            if ((unsigned)gy < HH && (unsigned)gx < WW)
                ld[k] = *(const bf16x8*)&in_hwc[(((size_t)(b * HH + gy) * WW) + gx) * CIN + icc2 * 32 + icq * 8];
        }
    };
    auto write_chunk = [&](int gi2, int k) {
        int t2 = gi2 / ICC, icc2 = gi2 % ICC;
        int y02 = yb + t2 * 4;
        unsigned short* buf = &sA[gi2 & 1][0];
        int e = tid + k * 256;
        if (e < 1584) {
            int r = e / 264, rem = e - r * 264;
            int x = rem >> 2, icq = rem & 3;
            int gy = y02 + r - 1, gx = x0 + x - 1;
            int c0 = icc2 * 32 + icq * 8;
            unsigned int w4[4];
            if ((unsigned)gy < HH && (unsigned)gx < WW) {
#pragma unroll
                for (int jp = 0; jp < 4; ++jp) {
                    float f0 = fmaxf(bf2f(((unsigned short*)&ld[k])[2 * jp]),     sMaxMu[c0 + 2 * jp]);
                    float f1 = fmaxf(bf2f(((unsigned short*)&ld[k])[2 * jp + 1]), sMaxMu[c0 + 2 * jp + 1]);
                    w4[jp] = cvtpk(f0, f1);
                }
            } else {
#pragma unroll
                for (int jp = 0; jp < 4; ++jp)
                    w4[jp] = (unsigned int)sMuBf[c0 + 2 * jp] |
                             ((unsigned int)sMuBf[c0 + 2 * jp + 1] << 16);
            }
            *(uint4*)&buf[(r * 264 + x * 4 + (icq ^ ((x >> 1) & 3))) * 8] =
                make_uint4(w4[0], w4[1], w4[2], w4[3]);
        }
    };

    f32x4 acc[4][4];
#pragma unroll
    for (int fp = 0; fp < 4; ++fp)
#pragma unroll
        for (int fo = 0; fo < 4; ++fo)
            acc[fp][fo] = (f32x4){0.f, 0.f, 0.f, 0.f};

    float bb[4][4];
#pragma unroll
    for (int fo = 0; fo < 4; ++fo) {
        float4 b4 = *(const float4*)&biasb[fo * 16 + g * 4];
        bb[fo][0] = b4.x; bb[fo][1] = b4.y; bb[fo][2] = b4.z; bb[fo][3] = b4.w;
    }
    float sjA[4][4] = {}, qjA[4][4] = {};

    // one tap: af from LDS, bfr from L2-resident global image
    auto tap = [&](int gi2, int kk) {
        const int icc2 = gi2 % ICC;
        const unsigned short* bufA = &sA[gi2 & 1][0];
        const int ky = kk / 3, kx = kk - ky * 3;
        bf16x8 af[4], bfr[4];
#pragma unroll
        for (int fp = 0; fp < 4; ++fp) {
            int xl = fp * 16 + lm + kx;
            int u  = (xl * 4 + g) ^ ((xl >> 1) & 3);
            af[fp] = *(const bf16x8*)(bufA + ((w + ky) * 264 + u) * 8);
        }
#pragma unroll
        for (int fo = 0; fo < 4; ++fo) {
            int ocr = fo * 16 + lm;
            size_t p = (size_t)icc2 * 2304 + kk * 256 + ocr * 4 + (g ^ ((ocr >> 1) & 3));
            bfr[fo] = *(const bf16x8*)&wtb[p * 8];
        }
#pragma unroll
        for (int fo = 0; fo < 4; ++fo)
#pragma unroll
            for (int fp = 0; fp < 4; ++fp)
                acc[fp][fo] = __builtin_amdgcn_mfma_f32_16x16x32_bf16(
                    bfr[fo], af[fp], acc[fp][fo], 0, 0, 0);
    };

    // ---- prologue: stage group 0 ----
    if (NORM == 0) {
        issueA_glds(0);
        __syncthreads();
    } else {
#pragma unroll
        for (int k = 0; k < 7; ++k) issue_chunk(0, k);
        __syncthreads();          // sMaxMu/sMuBf visible
#pragma unroll
        for (int k = 0; k < 7; ++k) write_chunk(0, k);
        __syncthreads();
    }

    // ---- group loop: 144 MFMA per barrier pair ----
    for (int gi = 0; gi < NG; ++gi) {
        const int icc = gi % ICC, t = gi / ICC;
        const bool more = (gi + 1 < NG);

        if (NORM == 0) {
            if (more) issueA_glds(gi + 1);
            __builtin_amdgcn_s_setprio(1);
#pragma unroll
            for (int kk = 0; kk < 9; ++kk) tap(gi, kk);
            __builtin_amdgcn_s_setprio(0);
        } else {
            if (more) {
#pragma unroll
                for (int k = 0; k < 4; ++k) issue_chunk(gi + 1, k);
            }
            __builtin_amdgcn_s_setprio(1);
#pragma unroll
            for (int kk = 0; kk < 4; ++kk) tap(gi, kk);
            __builtin_amdgcn_s_setprio(0);
            if (more) {
#pragma unroll
                for (int k = 0; k < 4; ++k) write_chunk(gi + 1, k);
#pragma unroll
                for (int k = 4; k < 7; ++k) issue_chunk(gi + 1, k);
            }
            __builtin_amdgcn_s_setprio(1);
#pragma unroll
            for (int kk = 4; kk < 9; ++kk) tap(gi, kk);
            __builtin_amdgcn_s_setprio(0);
            if (more) {
#pragma unroll
                for (int k = 4; k < 7; ++k) write_chunk(gi + 1, k);
            }
        }

        // ---- subtile epilogue: stores + stats accumulation, reset acc ----
        if (icc == ICC - 1) {
            const int row = yb + 4 * t + w;
#pragma unroll
            for (int fo = 0; fo < 4; ++fo) {
#pragma unroll
                for (int fp = 0; fp < 4; ++fp) {
                    float v0 = acc[fp][fo][0] + bb[fo][0], v1 = acc[fp][fo][1] + bb[fo][1];
                    float v2 = acc[fp][fo][2] + bb[fo][2], v3 = acc[fp][fo][3] + bb[fo][3];
                    sjA[fo][0] += v0; qjA[fo][0] += v0 * v0;
                    sjA[fo][1] += v1; qjA[fo][1] += v1 * v1;
                    sjA[fo][2] += v2; qjA[fo][2] += v2 * v2;
                    sjA[fo][3] += v3; qjA[fo][3] += v3 * v3;
                    uint2 st = make_uint2(cvtpk(v0, v1), cvtpk(v2, v3));
                    *(uint2*)&out_hwc[(((size_t)b * HH + row) * WW + x0 + fp * 16 + lm) * 64 + fo * 16 + g * 4] = st;
                    acc[fp][fo] = (f32x4){0.f, 0.f, 0.f, 0.f};
                }
            }
        }
        __syncthreads();
    }

    // ---- block-level stats partial ----
#pragma unroll
    for (int fo = 0; fo < 4; ++fo) {
#pragma unroll
        for (int m = 1; m <= 8; m <<= 1)
#pragma unroll
            for (int j = 0; j < 4; ++j) {
                sjA[fo][j] += __shfl_xor(sjA[fo][j], m);
                qjA[fo][j] += __shfl_xor(qjA[fo][j], m);
            }
        if (lm == 0) {
#pragma unroll
            for (int j = 0; j < 4; ++j) {
                sRedS [w * 64 + fo * 16 + g * 4 + j] = sjA[fo][j];
                sRedSS[w * 64 + fo * 16 + g * 4 + j] = qjA[fo][j];
            }
        }
    }
    __syncthreads();
    if (tid < 64) {
        float S = 0.f, SS = 0.f;
#pragma unroll
        for (int q = 0; q < 4; ++q) { S += sRedS[q * 64 + tid]; SS += sRedSS[q * 64 + tid]; }
        partials[((size_t)b * 100 + blockIdx.y * 5 + blockIdx.x) * 64 + tid] = make_float2(S, SS);
    }
}

// ---------------- partials -> (mean, rstd) ----------------
__global__ __launch_bounds__(256) void reduce_stats(const float2* __restrict__ partials,
                                                    float2* __restrict__ stats, int count)
{
    const int b  = blockIdx.x;
    const int oc = threadIdx.x & 63;
    const int q  = threadIdx.x >> 6;
    float s = 0.f, ss = 0.f;
    for (int i = q; i < count; i += 4) {
        float2 p = partials[((size_t)b * count + i) * 64 + oc];
        s += p.x; ss += p.y;
    }
    __shared__ float2 red[4][64];
    red[q][oc] = make_float2(s, ss);
    __syncthreads();
    if (threadIdx.x < 64) {
        float S = 0.f, SS = 0.f;
#pragma unroll
        for (int k = 0; k < 4; ++k) { S += red[k][threadIdx.x].x; SS += red[k][threadIdx.x].y; }
        const float n = (float)(HH * WW);
        float mean = S / n;
        float var  = fmaxf(SS / n - mean * mean, 0.f);
        stats[b * 64 + threadIdx.x] = make_float2(mean, rsqrtf(var + EPS));
    }
}

// ------- final: read h2 NHWC bf16, norm+relu, register-transpose, NCHW fp32 -------
__global__ __launch_bounds__(256) void finalize_t(const unsigned short* __restrict__ h2,
                                                  const float2* __restrict__ stats,
                                                  float* __restrict__ out)
{
    __shared__ float2 sSt[64];
    const int tid = threadIdx.x;
    const int b   = blockIdx.z;
    if (tid < 64) sSt[tid] = stats[b * 64 + tid];
    __syncthreads();
    const int r   = tid >> 6;
    const int px  = tid & 63;
    const int row = blockIdx.y * 4 + r;
    const int x   = blockIdx.x * 64 + px;
    const unsigned short* src = h2 + ((size_t)(b * HH + row) * WW + x) * 64;
    bf16x8 v[8];
#pragma unroll
    for (int cq = 0; cq < 8; ++cq) v[cq] = *(const bf16x8*)(src + cq * 8);
#pragma unroll
    for (int cq = 0; cq < 8; ++cq)
#pragma unroll
        for (int j = 0; j < 8; ++j) {
            int c = cq * 8 + j;
            float2 ms = sSt[c];
            float f = fmaxf((bf2f(((unsigned short*)&v[cq])[j]) - ms.x) * ms.y, 0.f);
            out[((size_t)(b * 64 + c) * HH + row) * WW + x] = f;
        }
}

extern "C" void kernel_launch(void* const* d_in, const int* in_sizes, int n_in,
                              void* d_out, int out_size, void* d_ws, size_t ws_size,
                              hipStream_t stream)
{
    const float* x  = (const float*)d_in[0];
    const float* w1 = (const float*)d_in[1];
    const float* b1 = (const float*)d_in[2];
    const float* w2 = (const float*)d_in[3];
    const float* b2 = (const float*)d_in[4];
    float* out = (float*)d_out;

    // ws layout (211,361,792 B, proven budget)
    char* ws = (char*)d_ws;
    unsigned short* h    = (unsigned short*)ws;                         // 105 MB NHWC bf16
    float2* partials     = (float2*)(ws + 104857600);                   // 1.6 MB
    float2* stats1       = (float2*)(ws + 104857600 + 1638400);
    float2* stats2       = (float2*)(ws + 104857600 + 1638400 + 4096);
    unsigned short* reg2 = (unsigned short*)(ws + 104857600 + 1638400 + 8192);
    unsigned short* x_hwc = reg2;   // 52 MB, dead after conv1
    unsigned short* h2    = reg2;   // 105 MB, conv2 output

    // weight scratch in tail of d_out (dead until finalize_t fully rewrites d_out last)
    char* ob = (char*)d_out + 209715200;
    float*          bias2b = (float*)(ob - 2048);                          // 8*64*4 B
    unsigned short* wt2b   = (unsigned short*)(ob - 2048 - 589824);        // 589,824 B
    unsigned short* wt2    = (unsigned short*)(ob - 2048 - 589824 - 73728);
    unsigned short* wt1    = (unsigned short*)(ob - 2048 - 589824 - 73728 - 36864);

    dim3 cgrid(5, 20, BB);   // 64px x-tiles, 16-row supertiles, batch

    wprep_swz<<<18, 256, 0, stream>>>(w1, w2, wt1, wt2);
    prep_hwc<<<dim3(5, HH, BB), 256, 0, stream>>>(x, x_hwc);

    // conv1: raw conv -> h (NHWC bf16) + stats partials
    conv_mfma<32, 0><<<cgrid, 256, 0, stream>>>(x_hwc, nullptr, wt1, b1, h, partials);
    reduce_stats<<<BB, 256, 0, stream>>>(partials, stats1, 100);
    // fold norm scale into per-batch conv2 weights + bias
    wfold<<<BB, 256, 0, stream>>>(wt2, b2, stats1, wt2b, bias2b);
    // conv2: staged max(h,mu) against folded weights -> h2 + partials
    conv_mfma<64, 1><<<cgrid, 256, 0, stream>>>(h, stats1, wt2b, bias2b, h2, partials);
    reduce_stats<<<BB, 256, 0, stream>>>(partials, stats2, 100);
    // norm(stats2)+relu + transpose -> d_out fp32 NCHW (fully rewrites d_out)
    finalize_t<<<dim3(5, 80, BB), 256, 0, stream>>>(h2, stats2, out);
}

// Round 15
// 426.880 us; speedup vs baseline: 1.7559x; 1.7559x over previous
//
#include <hip/hip_runtime.h>

#define HH 320
#define WW 320
#define PW 322
#define BB 8
static constexpr float EPS = 1e-5f;

typedef __attribute__((ext_vector_type(8))) short bf16x8;
typedef __attribute__((ext_vector_type(4))) float f32x4;

#define VMW(N) asm volatile("s_waitcnt vmcnt(" #N ")" ::: "memory")
#define LGKM0  asm volatile("s_waitcnt lgkmcnt(0)" ::: "memory")
#define SBAR() __builtin_amdgcn_s_barrier()
#define SCH0() __builtin_amdgcn_sched_barrier(0)

__device__ inline float bf2f(unsigned short u) {
    union { unsigned int i; float f; } v; v.i = ((unsigned int)u) << 16; return v.f;
}
__device__ inline unsigned short f2bf(float f) {
    union { float f; unsigned int i; } v; v.f = f;
    unsigned int r = v.i + 0x7fffu + ((v.i >> 16) & 1u);
    return (unsigned short)(r >> 16);
}
__device__ inline unsigned int cvtpk(float a, float b) {
    unsigned int r;
    asm volatile("v_cvt_pk_bf16_f32 %0, %1, %2" : "=v"(r) : "v"(a), "v"(b));
    return r;
}
__device__ inline void glds16(const void* g, void* l) {
    __builtin_amdgcn_global_load_lds(
        (const __attribute__((address_space(1))) unsigned int*)g,
        (__attribute__((address_space(3))) unsigned int*)l, 16, 0, 0);
}

// ---------------- NCHW fp32 -> padded NHWC bf16 (CIN=32, zero guards) ----------------
__global__ __launch_bounds__(256) void prep_pad(const float* __restrict__ in,
                                                unsigned short* __restrict__ xp)
{
    __shared__ float sT[32][65];
    const int tid = threadIdx.x;
    const int p0  = blockIdx.x * 64;   // padded col base (grid.x = 6)
    const int py  = blockIdx.y;        // padded row 0..321
    const int b   = blockIdx.z;
    const int gy  = py - 1;
    unsigned short* orow = xp + ((size_t)(b * PW + py) * PW) * 32;
    if ((unsigned)gy >= (unsigned)HH) {
        for (int e = tid; e < 64 * 32; e += 256) {
            int x = e >> 5, c = e & 31;
            int p = p0 + x;
            if (p < PW) orow[(size_t)p * 32 + c] = 0;
        }
        return;
    }
    for (int e = tid; e < 32 * 64; e += 256) {
        int c = e >> 6, i = e & 63;
        int gx = p0 + i - 1;
        sT[c][i] = ((unsigned)gx < (unsigned)WW)
                   ? in[(((size_t)(b * 32 + c) * HH) + gy) * WW + gx] : 0.f;
    }
    __syncthreads();
    for (int e = tid; e < 64 * 32; e += 256) {
        int x = e >> 5, c = e & 31;
        int p = p0 + x;
        if (p < PW) orow[(size_t)p * 32 + c] = f2bf(sT[c][x]);
    }
}

// ---------------- h_pad guards = -inf bf16 (so max(h,mu)=mu at borders) ----------------
__global__ __launch_bounds__(256) void init_guards(unsigned short* __restrict__ hp)
{
    int i = blockIdx.x * 256 + threadIdx.x;
    if (i >= BB * 1284) return;
    int b = i / 1284, p = i - b * 1284;
    int row, col;
    if (p < 322)      { row = 0;   col = p; }
    else if (p < 644) { row = 321; col = p - 322; }
    else { int q = p - 644; row = 1 + (q >> 1); col = (q & 1) ? 321 : 0; }
    unsigned short* d = hp + ((size_t)(b * PW + row) * PW + col) * 64;
#pragma unroll
    for (int k = 0; k < 64; ++k) d[k] = 0xFF80;   // -inf bf16
}

// ------ weights OIHW fp32 -> bank-swizzled bf16 images ------
__global__ __launch_bounds__(256) void wprep_swz(const float* __restrict__ w1,
                                                 const float* __restrict__ w2,
                                                 unsigned short* __restrict__ wt1,
                                                 unsigned short* __restrict__ wt2)
{
    int i = blockIdx.x * 256 + threadIdx.x;
    if (i < 2304) {
        int s = i & 3, oc = (i >> 2) & 63, kk = i >> 8;
        int icq = s ^ ((oc >> 1) & 3);
        const float* src = w1 + ((size_t)oc * 32 + icq * 8) * 9 + kk;
        unsigned short pk[8];
#pragma unroll
        for (int j = 0; j < 8; ++j) pk[j] = f2bf(src[j * 9]);
        *(bf16x8*)&wt1[(size_t)i * 8] = *(bf16x8*)pk;
    }
    if (i < 4608) {
        int icc = i / 2304, u = i - icc * 2304;
        int s = u & 3, oc = (u >> 2) & 63, kk = u >> 8;
        int icq = s ^ ((oc >> 1) & 3);
        const float* src = w2 + ((size_t)oc * 64 + icc * 32 + icq * 8) * 9 + kk;
        unsigned short pk[8];
#pragma unroll
        for (int j = 0; j < 8; ++j) pk[j] = f2bf(src[j * 9]);
        *(bf16x8*)&wt2[(size_t)i * 8] = *(bf16x8*)pk;
    }
}

// ------ fold conv1 InstanceNorm scale into conv2 weights (per batch) ------
__global__ __launch_bounds__(256) void wfold(const unsigned short* __restrict__ wt2,
                                             const float* __restrict__ b2,
                                             const float2* __restrict__ stats1,
                                             unsigned short* __restrict__ wt2b,
                                             float* __restrict__ bias2b)
{
    __shared__ float sMu[64], sR[64];
    __shared__ float sBias[256];
    const int b = blockIdx.x, tid = threadIdx.x;
    if (tid < 64) {
        float2 ms = stats1[b * 64 + tid];
        sMu[tid] = bf2f(f2bf(ms.x));
        sR[tid]  = ms.y;
    }
    __syncthreads();
    const int oc = tid & 63, rep = tid >> 6;
    float bsum = 0.f;
    for (int cs = rep * 2; cs < rep * 2 + 2; ++cs) {
        int icc = cs >> 2, s = cs & 3;
        int icq = s ^ ((oc >> 1) & 3);
        for (int kk = 0; kk < 9; ++kk) {
            size_t u = (size_t)icc * 2304 + kk * 256 + oc * 4 + s;
            bf16x8 v = *(const bf16x8*)&wt2[u * 8];
            unsigned short o8[8];
#pragma unroll
            for (int j = 0; j < 8; ++j) {
                int ic = icc * 32 + icq * 8 + j;
                unsigned short wb = f2bf(bf2f(((unsigned short*)&v)[j]) * sR[ic]);
                o8[j] = wb;
                bsum += bf2f(wb) * sMu[ic];
            }
            *(bf16x8*)&wt2b[((size_t)b * 4608 + u) * 8] = *(bf16x8*)o8;
        }
    }
    sBias[tid] = bsum;
    __syncthreads();
    if (tid < 64) {
        float t = sBias[tid] + sBias[tid + 64] + sBias[tid + 128] + sBias[tid + 192];
        bias2b[b * 64 + tid] = b2[tid] - t;
    }
}

// ================= conv1: counted-vmcnt pipeline (CIN=32) =================
__global__ __launch_bounds__(256, 2) void conv1_pipe(
    const unsigned short* __restrict__ xp,    // [B][322][322][32]
    const unsigned short* __restrict__ wt,    // 2304 units
    const float* __restrict__ bias,           // [64]
    unsigned short* __restrict__ hp,          // [B][322][322][64] (interior)
    float2* __restrict__ partials)            // [B*100][64]
{
    __shared__ __align__(16) unsigned short sA[2][1584 * 8];
    __shared__ __align__(16) unsigned short sW[2][768 * 8];
    __shared__ float sRedS[256], sRedSS[256];

    const int tid = threadIdx.x;
    const int XB  = blockIdx.x * 64;
    const int yb  = blockIdx.y * 16;
    const int b   = blockIdx.z;
    const int w = tid >> 6, l = tid & 63, lm = l & 15, g = l >> 4;

    auto issueA = [&](int gg, int bufi) {
        const int y0 = yb + gg * 4;
        unsigned short* buf = sA[bufi];
#pragma unroll
        for (int j = 0; j < 3; ++j) {
            const int hrow = 3 * w + j;
            const int r = hrow >> 1, half = hrow & 1;
            const unsigned short* rowb = xp + ((size_t)(b * PW + y0 + r) * PW + XB) * 32;
            unsigned short* dst = buf + (r * 264 + half * 132) * 8;
#pragma unroll
            for (int i = 0; i < 2; ++i) {
                int xu = half * 132 + i * 64 + l;
                int x = xu >> 2, cs = (xu & 3) ^ ((x >> 1) & 3);
                glds16(rowb + (size_t)x * 32 + cs * 8, dst + (size_t)(i * 64) * 8);
            }
            if (l < 4) {
                int xu = half * 132 + 128 + l;
                int x = xu >> 2, cs = (xu & 3) ^ ((x >> 1) & 3);
                glds16(rowb + (size_t)x * 32 + cs * 8, dst + (size_t)128 * 8);
            }
        }
    };
    auto issueW = [&](int kt, int bufi) {
        const unsigned short* wsrc = wt + (size_t)(kt * 768) * 8;
        unsigned short* dst = sW[bufi];
#pragma unroll
        for (int k = 0; k < 3; ++k)
            glds16(wsrc + (size_t)(k * 256 + w * 64 + l) * 8,
                   dst + (size_t)(k * 256 + w * 64) * 8);
    };

    f32x4 acc[4][4];
#pragma unroll
    for (int fp = 0; fp < 4; ++fp)
#pragma unroll
        for (int fo = 0; fo < 4; ++fo) acc[fp][fo] = (f32x4){0.f,0.f,0.f,0.f};

    float bb[4][4];
#pragma unroll
    for (int fo = 0; fo < 4; ++fo) {
        float4 b4 = *(const float4*)&bias[fo * 16 + g * 4];
        bb[fo][0] = b4.x; bb[fo][1] = b4.y; bb[fo][2] = b4.z; bb[fo][3] = b4.w;
    }
    float sjA[4][4] = {}, qjA[4][4] = {};

    auto compute = [&](int bufA, int bufW, int kt) {
        const unsigned short* A  = sA[bufA];
        const unsigned short* Wb = sW[bufW];
        __builtin_amdgcn_s_setprio(1);
#pragma unroll
        for (int kx = 0; kx < 3; ++kx) {
            bf16x8 af[4], bfr[4];
#pragma unroll
            for (int fp = 0; fp < 4; ++fp) {
                int xl = fp * 16 + lm + kx;
                int u  = (xl * 4 + g) ^ ((xl >> 1) & 3);
                af[fp] = *(const bf16x8*)(A + ((w + kt) * 264 + u) * 8);
            }
#pragma unroll
            for (int fo = 0; fo < 4; ++fo) {
                int ocr = fo * 16 + lm;
                bfr[fo] = *(const bf16x8*)(Wb + (kx * 256 + ocr * 4 + (g ^ ((ocr >> 1) & 3))) * 8);
            }
#pragma unroll
            for (int fo = 0; fo < 4; ++fo)
#pragma unroll
                for (int fp = 0; fp < 4; ++fp)
                    acc[fp][fo] = __builtin_amdgcn_mfma_f32_16x16x32_bf16(
                        bfr[fo], af[fp], acc[fp][fo], 0, 0, 0);
        }
        __builtin_amdgcn_s_setprio(0);
    };

    auto epilogue = [&](int t) {
        const int prow = yb + 4 * t + w + 1;
#pragma unroll
        for (int fo = 0; fo < 4; ++fo) {
#pragma unroll
            for (int fp = 0; fp < 4; ++fp) {
                float v0 = acc[fp][fo][0] + bb[fo][0], v1 = acc[fp][fo][1] + bb[fo][1];
                float v2 = acc[fp][fo][2] + bb[fo][2], v3 = acc[fp][fo][3] + bb[fo][3];
                sjA[fo][0] += v0; qjA[fo][0] += v0 * v0;
                sjA[fo][1] += v1; qjA[fo][1] += v1 * v1;
                sjA[fo][2] += v2; qjA[fo][2] += v2 * v2;
                sjA[fo][3] += v3; qjA[fo][3] += v3 * v3;
                uint2 st = make_uint2(cvtpk(v0, v1), cvtpk(v2, v3));
                *(uint2*)&hp[((size_t)(b * PW + prow) * PW + XB + 1 + fp * 16 + lm) * 64 + fo * 16 + g * 4] = st;
                acc[fp][fo] = (f32x4){0.f,0.f,0.f,0.f};
            }
        }
    };

    // prologue: stage group 0 + slab 0, full drain
    issueW(0, 0);
    issueA(0, 0);
    __syncthreads();

    for (int gi = 0; gi < 4; ++gi) {
        const int ba = gi & 1;
        // P0: need A(gi), W(gi,0); newer = stores16 + W(gi,1)3
        issueW(1, ba ^ 1);
        VMW(19); SBAR(); SCH0();
        compute(ba, ba, 0);
        SBAR(); SCH0();
        // P1: need W(gi,1); newer = W(gi,2)3
        issueW(2, ba);
        VMW(3); SBAR(); SCH0();
        compute(ba, ba ^ 1, 1);
        SBAR(); SCH0();
        // P2: need W(gi,2); newer = W(next,0)3 + A(next)9
        issueW(0, ba ^ 1);
        issueA((gi < 3) ? gi + 1 : 3, ba ^ 1);
        VMW(12); SBAR(); SCH0();
        compute(ba, ba, 2);
        epilogue(gi);
        SBAR(); SCH0();
    }
    __syncthreads();

#pragma unroll
    for (int fo = 0; fo < 4; ++fo) {
#pragma unroll
        for (int m = 1; m <= 8; m <<= 1)
#pragma unroll
            for (int j = 0; j < 4; ++j) {
                sjA[fo][j] += __shfl_xor(sjA[fo][j], m);
                qjA[fo][j] += __shfl_xor(qjA[fo][j], m);
            }
        if (lm == 0) {
#pragma unroll
            for (int j = 0; j < 4; ++j) {
                sRedS [w * 64 + fo * 16 + g * 4 + j] = sjA[fo][j];
                sRedSS[w * 64 + fo * 16 + g * 4 + j] = qjA[fo][j];
            }
        }
    }
    __syncthreads();
    if (tid < 64) {
        float S = 0.f, SS = 0.f;
#pragma unroll
        for (int q = 0; q < 4; ++q) { S += sRedS[q * 64 + tid]; SS += sRedSS[q * 64 + tid]; }
        partials[((size_t)b * 100 + blockIdx.y * 5 + blockIdx.x) * 64 + tid] = make_float2(S, SS);
    }
}

// ================= conv2: counted-vmcnt pipeline (CIN=64, fused norm) =================
__global__ __launch_bounds__(256, 2) void conv2_pipe(
    const unsigned short* __restrict__ hpin,  // [B][322][322][64] (-inf guards)
    const float2* __restrict__ stats_in,      // [B*64]
    const unsigned short* __restrict__ wt,    // per-batch folded images
    const float* __restrict__ bias,           // per-batch [B*64]
    unsigned short* __restrict__ h2,          // [B][320][320][64]
    float2* __restrict__ partials)            // [B*100][64]
{
    __shared__ __align__(16) unsigned short sA[2][1584 * 8];
    __shared__ __align__(16) unsigned short sW[2][768 * 8];
    __shared__ float sRedS[256], sRedSS[256];
    __shared__ float sMaxMu[64];

    const int tid = threadIdx.x;
    const int XB  = blockIdx.x * 64;
    const int yb  = blockIdx.y * 16;
    const int b   = blockIdx.z;
    const int w = tid >> 6, l = tid & 63, lm = l & 15, g = l >> 4;

    const unsigned short* wtb = wt + (size_t)b * 4608 * 8;

    if (tid < 64) {
        float2 ms = stats_in[b * 64 + tid];
        sMaxMu[tid] = bf2f(f2bf(ms.x));
    }

    bf16x8 ld[7];
    auto issueR = [&](int gg) {
        const int t2 = gg >> 1, icc2 = gg & 1;
        const int y0 = yb + t2 * 4;
#pragma unroll
        for (int k = 0; k < 7; ++k) {
            int e = w * 396 + k * 64 + l;
            if (k < 6 || l < 12) {
                int r = e / 264, xu = e - r * 264;
                int x = xu >> 2, icq = xu & 3;
                ld[k] = *(const bf16x8*)&hpin[((size_t)(b * PW + y0 + r) * PW + XB + x) * 64 + icc2 * 32 + icq * 8];
            }
        }
    };
    auto writeA = [&](int gg) {
        unsigned short* buf = sA[gg & 1];
        const int c0b = (gg & 1) * 32;
#pragma unroll
        for (int k = 0; k < 7; ++k) {
            int e = w * 396 + k * 64 + l;
            if (k < 6 || l < 12) {
                int r = e / 264, xu = e - r * 264;
                int x = xu >> 2, icq = xu & 3;
                int c0 = c0b + icq * 8;
                unsigned int w4[4];
#pragma unroll
                for (int jp = 0; jp < 4; ++jp) {
                    float f0 = fmaxf(bf2f(((unsigned short*)&ld[k])[2 * jp]),     sMaxMu[c0 + 2 * jp]);
                    float f1 = fmaxf(bf2f(((unsigned short*)&ld[k])[2 * jp + 1]), sMaxMu[c0 + 2 * jp + 1]);
                    w4[jp] = cvtpk(f0, f1);
                }
                *(uint4*)&buf[(r * 264 + x * 4 + (icq ^ ((x >> 1) & 3))) * 8] =
                    make_uint4(w4[0], w4[1], w4[2], w4[3]);
            }
        }
    };
    auto issueW = [&](int icc2, int kt, int bufi) {
        const unsigned short* wsrc = wtb + (size_t)(icc2 * 2304 + kt * 768) * 8;
        unsigned short* dst = sW[bufi];
#pragma unroll
        for (int k = 0; k < 3; ++k)
            glds16(wsrc + (size_t)(k * 256 + w * 64 + l) * 8,
                   dst + (size_t)(k * 256 + w * 64) * 8);
    };

    f32x4 acc[4][4];
#pragma unroll
    for (int fp = 0; fp < 4; ++fp)
#pragma unroll
        for (int fo = 0; fo < 4; ++fo) acc[fp][fo] = (f32x4){0.f,0.f,0.f,0.f};

    float bb[4][4];
#pragma unroll
    for (int fo = 0; fo < 4; ++fo) {
        float4 b4 = *(const float4*)&bias[b * 64 + fo * 16 + g * 4];
        bb[fo][0] = b4.x; bb[fo][1] = b4.y; bb[fo][2] = b4.z; bb[fo][3] = b4.w;
    }
    float sjA[4][4] = {}, qjA[4][4] = {};

    auto compute = [&](int bufA, int bufW, int kt) {
        const unsigned short* A  = sA[bufA];
        const unsigned short* Wb = sW[bufW];
        __builtin_amdgcn_s_setprio(1);
#pragma unroll
        for (int kx = 0; kx < 3; ++kx) {
            bf16x8 af[4], bfr[4];
#pragma unroll
            for (int fp = 0; fp < 4; ++fp) {
                int xl = fp * 16 + lm + kx;
                int u  = (xl * 4 + g) ^ ((xl >> 1) & 3);
                af[fp] = *(const bf16x8*)(A + ((w + kt) * 264 + u) * 8);
            }
#pragma unroll
            for (int fo = 0; fo < 4; ++fo) {
                int ocr = fo * 16 + lm;
                bfr[fo] = *(const bf16x8*)(Wb + (kx * 256 + ocr * 4 + (g ^ ((ocr >> 1) & 3))) * 8);
            }
#pragma unroll
            for (int fo = 0; fo < 4; ++fo)
#pragma unroll
                for (int fp = 0; fp < 4; ++fp)
                    acc[fp][fo] = __builtin_amdgcn_mfma_f32_16x16x32_bf16(
                        bfr[fo], af[fp], acc[fp][fo], 0, 0, 0);
        }
        __builtin_amdgcn_s_setprio(0);
    };

    auto epilogue = [&](int t) {
        const int row = yb + 4 * t + w;
#pragma unroll
        for (int fo = 0; fo < 4; ++fo) {
#pragma unroll
            for (int fp = 0; fp < 4; ++fp) {
                float v0 = acc[fp][fo][0] + bb[fo][0], v1 = acc[fp][fo][1] + bb[fo][1];
                float v2 = acc[fp][fo][2] + bb[fo][2], v3 = acc[fp][fo][3] + bb[fo][3];
                sjA[fo][0] += v0; qjA[fo][0] += v0 * v0;
                sjA[fo][1] += v1; qjA[fo][1] += v1 * v1;
                sjA[fo][2] += v2; qjA[fo][2] += v2 * v2;
                sjA[fo][3] += v3; qjA[fo][3] += v3 * v3;
                uint2 st = make_uint2(cvtpk(v0, v1), cvtpk(v2, v3));
                *(uint2*)&h2[(((size_t)b * HH + row) * WW + XB + fp * 16 + lm) * 64 + fo * 16 + g * 4] = st;
                acc[fp][fo] = (f32x4){0.f,0.f,0.f,0.f};
            }
        }
    };

    // prologue
    issueW(0, 0, 0);
    issueR(0);
    __syncthreads();        // drains vm/lgkm; stats visible
    writeA(0);
    __syncthreads();

#define C2GROUP(GI, VMP0)                                                   \
    {                                                                       \
        const int gi_ = (GI);                                               \
        const int ba_ = gi_ & 1;                                            \
        issueR((gi_ < 7) ? gi_ + 1 : 7);                                    \
        issueW(ba_, 1, ba_ ^ 1);                                            \
        VMW(VMP0); SBAR(); SCH0();                                          \
        compute(ba_, ba_, 0);                                               \
        SBAR(); SCH0();                                                     \
        issueW(ba_, 2, ba_);                                                \
        VMW(3); SBAR(); SCH0();                                             \
        compute(ba_, ba_ ^ 1, 1);                                           \
        SBAR(); SCH0();                                                     \
        issueW(ba_ ^ 1, 0, ba_ ^ 1);                                        \
        VMW(3); SBAR(); SCH0();                                             \
        compute(ba_, ba_, 2);                                               \
        if (ba_ == 1) epilogue(gi_ >> 1);                                   \
        if (gi_ < 7) writeA(gi_ + 1);                                       \
        LGKM0;                                                              \
        SBAR(); SCH0();                                                     \
    }

    for (int gp = 0; gp < 4; ++gp) {
        C2GROUP(gp * 2,     26);
        C2GROUP(gp * 2 + 1, 10);
    }
#undef C2GROUP

    __syncthreads();
#pragma unroll
    for (int fo = 0; fo < 4; ++fo) {
#pragma unroll
        for (int m = 1; m <= 8; m <<= 1)
#pragma unroll
            for (int j = 0; j < 4; ++j) {
                sjA[fo][j] += __shfl_xor(sjA[fo][j], m);
                qjA[fo][j] += __shfl_xor(qjA[fo][j], m);
            }
        if (lm == 0) {
#pragma unroll
            for (int j = 0; j < 4; ++j) {
                sRedS [w * 64 + fo * 16 + g * 4 + j] = sjA[fo][j];
                sRedSS[w * 64 + fo * 16 + g * 4 + j] = qjA[fo][j];
            }
        }
    }
    __syncthreads();
    if (tid < 64) {
        float S = 0.f, SS = 0.f;
#pragma unroll
        for (int q = 0; q < 4; ++q) { S += sRedS[q * 64 + tid]; SS += sRedSS[q * 64 + tid]; }
        partials[((size_t)b * 100 + blockIdx.y * 5 + blockIdx.x) * 64 + tid] = make_float2(S, SS);
    }
}

// ---------------- partials -> (mean, rstd) ----------------
__global__ __launch_bounds__(256) void reduce_stats(const float2* __restrict__ partials,
                                                    float2* __restrict__ stats, int count)
{
    const int b  = blockIdx.x;
    const int oc = threadIdx.x & 63;
    const int q  = threadIdx.x >> 6;
    float s = 0.f, ss = 0.f;
    for (int i = q; i < count; i += 4) {
        float2 p = partials[((size_t)b * count + i) * 64 + oc];
        s += p.x; ss += p.y;
    }
    __shared__ float2 red[4][64];
    red[q][oc] = make_float2(s, ss);
    __syncthreads();
    if (threadIdx.x < 64) {
        float S = 0.f, SS = 0.f;
#pragma unroll
        for (int k = 0; k < 4; ++k) { S += red[k][threadIdx.x].x; SS += red[k][threadIdx.x].y; }
        const float n = (float)(HH * WW);
        float mean = S / n;
        float var  = fmaxf(SS / n - mean * mean, 0.f);
        stats[b * 64 + threadIdx.x] = make_float2(mean, rsqrtf(var + EPS));
    }
}

// ------- final: read h2 NHWC bf16, norm+relu, register-transpose, NCHW fp32 -------
__global__ __launch_bounds__(256) void finalize_t(const unsigned short* __restrict__ h2,
                                                  const float2* __restrict__ stats,
                                                  float* __restrict__ out)
{
    __shared__ float2 sSt[64];
    const int tid = threadIdx.x;
    const int b   = blockIdx.z;
    if (tid < 64) sSt[tid] = stats[b * 64 + tid];
    __syncthreads();
    const int r   = tid >> 6;
    const int px  = tid & 63;
    const int row = blockIdx.y * 4 + r;
    const int x   = blockIdx.x * 64 + px;
    const unsigned short* src = h2 + ((size_t)(b * HH + row) * WW + x) * 64;
    bf16x8 v[8];
#pragma unroll
    for (int cq = 0; cq < 8; ++cq) v[cq] = *(const bf16x8*)(src + cq * 8);
#pragma unroll
    for (int cq = 0; cq < 8; ++cq)
#pragma unroll
        for (int j = 0; j < 8; ++j) {
            int c = cq * 8 + j;
            float2 ms = sSt[c];
            float f = fmaxf((bf2f(((unsigned short*)&v[cq])[j]) - ms.x) * ms.y, 0.f);
            out[((size_t)(b * 64 + c) * HH + row) * WW + x] = f;
        }
}

extern "C" void kernel_launch(void* const* d_in, const int* in_sizes, int n_in,
                              void* d_out, int out_size, void* d_ws, size_t ws_size,
                              hipStream_t stream)
{
    const float* x  = (const float*)d_in[0];
    const float* w1 = (const float*)d_in[1];
    const float* b1 = (const float*)d_in[2];
    const float* w2 = (const float*)d_in[3];
    const float* b2 = (const float*)d_in[4];
    float* out = (float*)d_out;

    // ws: h_pad (106,172,416) | region2 = x_pad(53,086,208) then h2(104,857,600) | stats
    char* ws = (char*)d_ws;
    unsigned short* hp   = (unsigned short*)ws;
    unsigned short* reg2 = (unsigned short*)(ws + 106172416);
    unsigned short* xp   = reg2;     // dead after conv1
    unsigned short* h2   = reg2;     // conv2 output
    float2* stats1 = (float2*)(ws + 106172416 + 104857600);
    float2* stats2 = stats1 + 512;

    // d_out tail scratch (all dead before finalize_t rewrites d_out)
    char* ob = (char*)d_out + 209715200;
    float2*         partials = (float2*)(ob - 409600);                      // 409,600 B
    float*          bias2b   = (float*)(ob - 409600 - 2048);
    unsigned short* wt2b     = (unsigned short*)(ob - 409600 - 2048 - 589824);
    unsigned short* wt2      = (unsigned short*)(ob - 409600 - 2048 - 589824 - 73728);
    unsigned short* wt1      = (unsigned short*)(ob - 409600 - 2048 - 589824 - 73728 - 36864);

    dim3 cgrid(5, 20, BB);

    wprep_swz<<<18, 256, 0, stream>>>(w1, w2, wt1, wt2);
    init_guards<<<(BB * 1284 + 255) / 256, 256, 0, stream>>>(hp);
    prep_pad<<<dim3(6, PW, BB), 256, 0, stream>>>(x, xp);

    conv1_pipe<<<cgrid, 256, 0, stream>>>(xp, wt1, b1, hp, partials);
    reduce_stats<<<BB, 256, 0, stream>>>(partials, stats1, 100);
    wfold<<<BB, 256, 0, stream>>>(wt2, b2, stats1, wt2b, bias2b);
    conv2_pipe<<<cgrid, 256, 0, stream>>>(hp, stats1, wt2b, bias2b, h2, partials);
    reduce_stats<<<BB, 256, 0, stream>>>(partials, stats2, 100);
    finalize_t<<<dim3(5, 80, BB), 256, 0, stream>>>(h2, stats2, out);
}

// Round 16
// 334.391 us; speedup vs baseline: 2.2415x; 1.2766x over previous
//
#include <hip/hip_runtime.h>

#define HH 320
#define WW 320
#define BB 8
static constexpr float EPS = 1e-5f;

typedef __attribute__((ext_vector_type(8))) short bf16x8;
typedef __attribute__((ext_vector_type(4))) float f32x4;

__device__ inline float bf2f(unsigned short u) {
    union { unsigned int i; float f; } v; v.i = ((unsigned int)u) << 16; return v.f;
}
__device__ inline unsigned short f2bf(float f) {
    union { float f; unsigned int i; } v; v.f = f;
    unsigned int r = v.i + 0x7fffu + ((v.i >> 16) & 1u);
    return (unsigned short)(r >> 16);
}
__device__ inline unsigned int cvtpk(float a, float b) {   // lo16=bf16(a), hi16=bf16(b)
    unsigned int r;
    asm volatile("v_cvt_pk_bf16_f32 %0, %1, %2" : "=v"(r) : "v"(a), "v"(b));
    return r;
}
__device__ inline void glds16(const void* g, void* l) {
    __builtin_amdgcn_global_load_lds(
        (const __attribute__((address_space(1))) unsigned int*)g,
        (__attribute__((address_space(3))) unsigned int*)l, 16, 0, 0);
}

// ---------------- NCHW fp32 -> NHWC bf16 (CIN=32) ----------------
__global__ __launch_bounds__(256) void prep_hwc(const float* __restrict__ in,
                                                unsigned short* __restrict__ out)
{
    __shared__ float sT[32][65];
    const int tid = threadIdx.x;
    const int x0  = blockIdx.x * 64;
    const int y   = blockIdx.y;
    const int b   = blockIdx.z;
    for (int e = tid; e < 32 * 64; e += 256) {
        int c = e >> 6, x = e & 63;
        sT[c][x] = in[(((size_t)(b * 32 + c) * HH) + y) * WW + x0 + x];
    }
    __syncthreads();
    for (int e = tid; e < 64 * 32; e += 256) {
        int x = e >> 5, c = e & 31;
        out[((((size_t)b * HH + y) * WW) + x0 + x) * 32 + c] = f2bf(sT[c][x]);
    }
}

// ------ weights OIHW fp32 -> bank-swizzled bf16 glds-ready images ------
__global__ __launch_bounds__(256) void wprep_swz(const float* __restrict__ w1,
                                                 const float* __restrict__ w2,
                                                 unsigned short* __restrict__ wt1,
                                                 unsigned short* __restrict__ wt2)
{
    int i = blockIdx.x * 256 + threadIdx.x;
    if (i < 2304) {
        int s = i & 3, oc = (i >> 2) & 63, kk = i >> 8;
        int icq = s ^ ((oc >> 1) & 3);
        const float* src = w1 + ((size_t)oc * 32 + icq * 8) * 9 + kk;
        unsigned short pk[8];
#pragma unroll
        for (int j = 0; j < 8; ++j) pk[j] = f2bf(src[j * 9]);
        *(bf16x8*)&wt1[(size_t)i * 8] = *(bf16x8*)pk;
    }
    if (i < 4608) {
        int icc = i / 2304, u = i - icc * 2304;
        int s = u & 3, oc = (u >> 2) & 63, kk = u >> 8;
        int icq = s ^ ((oc >> 1) & 3);
        const float* src = w2 + ((size_t)oc * 64 + icc * 32 + icq * 8) * 9 + kk;
        unsigned short pk[8];
#pragma unroll
        for (int j = 0; j < 8; ++j) pk[j] = f2bf(src[j * 9]);
        *(bf16x8*)&wt2[(size_t)i * 8] = *(bf16x8*)pk;
    }
}

// ------ fused: reduce conv1 partials -> stats1, then fold scale into wt2b ------
__global__ __launch_bounds__(256) void fold_stats(const float2* __restrict__ partials, // [B*100][64]
                                                  const float* __restrict__ b2,
                                                  const unsigned short* __restrict__ wt2,
                                                  float2* __restrict__ stats1,
                                                  unsigned short* __restrict__ wt2b,
                                                  float* __restrict__ bias2b)
{
    __shared__ float2 red[4][64];
    __shared__ float sMu[64], sR[64];
    __shared__ float sBias[256];
    const int b = blockIdx.x, tid = threadIdx.x;
    const int oc = tid & 63, q = tid >> 6;

    float s = 0.f, ss = 0.f;
    for (int i = q; i < 100; i += 4) {
        float2 p = partials[((size_t)b * 100 + i) * 64 + oc];
        s += p.x; ss += p.y;
    }
    red[q][oc] = make_float2(s, ss);
    __syncthreads();
    if (tid < 64) {
        float S = 0.f, SS = 0.f;
#pragma unroll
        for (int k = 0; k < 4; ++k) { S += red[k][tid].x; SS += red[k][tid].y; }
        const float n = (float)(HH * WW);
        float mean = S / n;
        float var  = fmaxf(SS / n - mean * mean, 0.f);
        float rstd = rsqrtf(var + EPS);
        stats1[b * 64 + tid] = make_float2(mean, rstd);
        sMu[tid] = bf2f(f2bf(mean));   // mu_bf, consistent with staged pads
        sR[tid]  = rstd;
    }
    __syncthreads();

    float bsum = 0.f;
    for (int cs = q * 2; cs < q * 2 + 2; ++cs) {
        int icc = cs >> 2, sdx = cs & 3;
        int icq = sdx ^ ((oc >> 1) & 3);
        for (int kk = 0; kk < 9; ++kk) {
            size_t u = (size_t)icc * 2304 + kk * 256 + oc * 4 + sdx;
            bf16x8 v = *(const bf16x8*)&wt2[u * 8];
            unsigned short o8[8];
#pragma unroll
            for (int j = 0; j < 8; ++j) {
                int ic = icc * 32 + icq * 8 + j;
                unsigned short wb = f2bf(bf2f(((unsigned short*)&v)[j]) * sR[ic]);
                o8[j] = wb;
                bsum += bf2f(wb) * sMu[ic];
            }
            *(bf16x8*)&wt2b[((size_t)b * 4608 + u) * 8] = *(bf16x8*)o8;
        }
    }
    sBias[tid] = bsum;
    __syncthreads();
    if (tid < 64) {
        float t = sBias[tid] + sBias[tid + 64] + sBias[tid + 128] + sBias[tid + 192];
        bias2b[b * 64 + tid] = b2[tid] - t;
    }
}

// ========== conv1: r13 supertile 2-phase (CIN=32), verified ==========
__global__ __launch_bounds__(256, 2) void conv1_super(
    const unsigned short* __restrict__ in_hwc,   // [B][H][W][32] bf16
    const unsigned short* __restrict__ wt,       // 2304 units
    const float* __restrict__ bias,              // [64]
    unsigned short* __restrict__ out_hwc,        // [B][H][W][64] bf16
    float2* __restrict__ partials)               // [B*100][64]
{
    constexpr int NG = 4;
    constexpr int NS = 12;

    __shared__ __align__(16) unsigned short sA[2][6 * 264 * 8];
    __shared__ __align__(16) unsigned short sWb[2][768 * 8];
    __shared__ float sRedS[256];
    __shared__ float sRedSS[256];

    const int tid = threadIdx.x;
    const int x0  = blockIdx.x * 64;
    const int yb  = blockIdx.y * 16;
    const int b   = blockIdx.z;
    const int w   = tid >> 6;
    const int l   = tid & 63;
    const int lm  = l & 15;
    const int g   = l >> 4;

    auto stage_slab = [&](int s2, int buf) {
        int kt2 = s2 % 3;
        const unsigned short* wsrc = wt + (size_t)(kt2 * 768) * 8;
        unsigned short* dst = &sWb[buf][0];
#pragma unroll
        for (int k = 0; k < 3; ++k)
            glds16(wsrc + (size_t)(k * 256 + w * 64 + l) * 8,
                   dst + (size_t)(k * 256 + w * 64) * 8);
    };

    auto issueA_glds = [&](int gi2) {
        int y02 = yb + gi2 * 4;
        unsigned short* buf = &sA[gi2 & 1][0];
        for (int r = w; r < 6; r += 4) {
            int gy = y02 + r - 1;
            unsigned short* ldsrow = buf + r * 2112;
            if ((unsigned)gy < HH) {
                const unsigned short* rowbase =
                    in_hwc + ((size_t)(b * HH + gy) * WW) * 32;
#pragma unroll
                for (int i = 0; i < 4; ++i) {
                    int u  = 4 + i * 64 + l;
                    int x  = u >> 2;
                    int cs = (u & 3) ^ ((x >> 1) & 3);
                    glds16(rowbase + (size_t)(x0 + x - 1) * 32 + cs * 8,
                           ldsrow + (size_t)(4 + i * 64) * 8);
                }
            } else {
                for (int u2 = l; u2 < 264; u2 += 64)
                    *(bf16x8*)(ldsrow + u2 * 8) = (bf16x8){0,0,0,0,0,0,0,0};
            }
        }
        if (tid < 48) {
            int icq = tid & 3, side = (tid >> 2) & 1, r = tid >> 3;
            int xs = side ? 65 : 0;
            int gy = y02 + r - 1, gx = x0 + xs - 1;
            bf16x8 v = (bf16x8){0,0,0,0,0,0,0,0};
            if ((unsigned)gy < HH && (unsigned)gx < WW)
                v = *(const bf16x8*)&in_hwc[(((size_t)(b * HH + gy) * WW) + gx) * 32 + icq * 8];
            *(bf16x8*)&buf[(r * 264 + xs * 4 + icq) * 8] = v;
        }
    };

    f32x4 acc[4][4];
#pragma unroll
    for (int fp = 0; fp < 4; ++fp)
#pragma unroll
        for (int fo = 0; fo < 4; ++fo)
            acc[fp][fo] = (f32x4){0.f, 0.f, 0.f, 0.f};

    float bb[4][4];
#pragma unroll
    for (int fo = 0; fo < 4; ++fo) {
        float4 b4 = *(const float4*)&bias[fo * 16 + g * 4];
        bb[fo][0] = b4.x; bb[fo][1] = b4.y; bb[fo][2] = b4.z; bb[fo][3] = b4.w;
    }
    float sjA[4][4] = {}, qjA[4][4] = {};

    stage_slab(0, 0);
    issueA_glds(0);
    __syncthreads();

    for (int s = 0; s < NS; ++s) {
        const int kt = s % 3;
        const int gi = s / 3;

        if (s + 1 < NS) stage_slab(s + 1, (s + 1) & 1);
        if (kt == 0 && gi + 1 < NG) issueA_glds(gi + 1);

        {
            const unsigned short* bufA = &sA[gi & 1][0];
            const unsigned short* bufW = &sWb[s & 1][0];
            __builtin_amdgcn_s_setprio(1);
#pragma unroll
            for (int kx = 0; kx < 3; ++kx) {
                bf16x8 af[4], bfr[4];
#pragma unroll
                for (int fp = 0; fp < 4; ++fp) {
                    int xl = fp * 16 + lm + kx;
                    int u  = (xl * 4 + g) ^ ((xl >> 1) & 3);
                    af[fp] = *(const bf16x8*)(bufA + ((w + kt) * 264 + u) * 8);
                }
#pragma unroll
                for (int fo = 0; fo < 4; ++fo) {
                    int ocr = fo * 16 + lm;
                    int p   = (kx * 64 + ocr) * 4 + (g ^ ((ocr >> 1) & 3));
                    bfr[fo] = *(const bf16x8*)(bufW + p * 8);
                }
#pragma unroll
                for (int fo = 0; fo < 4; ++fo)
#pragma unroll
                    for (int fp = 0; fp < 4; ++fp)
                        acc[fp][fo] = __builtin_amdgcn_mfma_f32_16x16x32_bf16(
                            bfr[fo], af[fp], acc[fp][fo], 0, 0, 0);
            }
            __builtin_amdgcn_s_setprio(0);
        }

        if (kt == 2) {
            const int row = yb + 4 * gi + w;
#pragma unroll
            for (int fo = 0; fo < 4; ++fo) {
#pragma unroll
                for (int fp = 0; fp < 4; ++fp) {
                    float v0 = acc[fp][fo][0] + bb[fo][0], v1 = acc[fp][fo][1] + bb[fo][1];
                    float v2 = acc[fp][fo][2] + bb[fo][2], v3 = acc[fp][fo][3] + bb[fo][3];
                    sjA[fo][0] += v0; qjA[fo][0] += v0 * v0;
                    sjA[fo][1] += v1; qjA[fo][1] += v1 * v1;
                    sjA[fo][2] += v2; qjA[fo][2] += v2 * v2;
                    sjA[fo][3] += v3; qjA[fo][3] += v3 * v3;
                    uint2 st = make_uint2(cvtpk(v0, v1), cvtpk(v2, v3));
                    *(uint2*)&out_hwc[(((size_t)b * HH + row) * WW + x0 + fp * 16 + lm) * 64 + fo * 16 + g * 4] = st;
                    acc[fp][fo] = (f32x4){0.f, 0.f, 0.f, 0.f};
                }
            }
        }
        __syncthreads();
    }

#pragma unroll
    for (int fo = 0; fo < 4; ++fo) {
#pragma unroll
        for (int m = 1; m <= 8; m <<= 1)
#pragma unroll
            for (int j = 0; j < 4; ++j) {
                sjA[fo][j] += __shfl_xor(sjA[fo][j], m);
                qjA[fo][j] += __shfl_xor(qjA[fo][j], m);
            }
        if (lm == 0) {
#pragma unroll
            for (int j = 0; j < 4; ++j) {
                sRedS [w * 64 + fo * 16 + g * 4 + j] = sjA[fo][j];
                sRedSS[w * 64 + fo * 16 + g * 4 + j] = qjA[fo][j];
            }
        }
    }
    __syncthreads();
    if (tid < 64) {
        float S = 0.f, SS = 0.f;
#pragma unroll
        for (int q = 0; q < 4; ++q) { S += sRedS[q * 64 + tid]; SS += sRedSS[q * 64 + tid]; }
        partials[((size_t)b * 100 + blockIdx.y * 5 + blockIdx.x) * 64 + tid] = make_float2(S, SS);
    }
}

// ========== conv2: r12 (256,3) kt-slab (CIN=64, staged max(h,mu)), verified ==========
__global__ __launch_bounds__(256, 3) void conv2_tile(
    const unsigned short* __restrict__ in_hwc,   // [B][H][W][64] bf16
    const float2* __restrict__ stats_in,         // [B*64]
    const unsigned short* __restrict__ wt,       // per-batch folded images
    const float* __restrict__ bias,              // per-batch [B*64]
    unsigned short* __restrict__ out_hwc,        // [B][H][W][64] bf16
    float2* __restrict__ partials)               // [B*400][64]
{
    __shared__ __align__(16) char smem[38912];
    unsigned short* sA    = (unsigned short*)smem;              // 25344 B
    unsigned short* sW    = (unsigned short*)(smem + 25344);    // 12288 B
    float*          sMaxMu= (float*)(smem + 37632);             // 256 B
    unsigned short* sMuBf = (unsigned short*)(smem + 37888);    // 128 B
    float* sRedS  = (float*)smem;                               // epilogue alias (sA dead)
    float* sRedSS = (float*)(smem + 1024);

    const int tid = threadIdx.x;
    const int x0  = blockIdx.x * 64;
    const int y0  = blockIdx.y * 4;
    const int b   = blockIdx.z;
    const int w   = tid >> 6;
    const int l   = tid & 63;
    const int lm  = l & 15;
    const int g   = l >> 4;

    const unsigned short* wtb = wt + (size_t)b * 4608 * 8;
    const float* biasb        = bias + b * 64;

    if (tid < 64) {
        float2 ms = stats_in[b * 64 + tid];
        unsigned short mb = f2bf(ms.x);
        sMuBf[tid]  = mb;
        sMaxMu[tid] = bf2f(mb);
    }

    f32x4 acc[4][4];
#pragma unroll
    for (int fp = 0; fp < 4; ++fp)
#pragma unroll
        for (int fo = 0; fo < 4; ++fo)
            acc[fp][fo] = (f32x4){0.f, 0.f, 0.f, 0.f};

    for (int icc = 0; icc < 2; ++icc) {
        __syncthreads();

#pragma unroll
        for (int k = 0; k < 7; ++k) {
            int e = tid + k * 256;
            if (e < 1584) {
                int r = e / 264, rem = e - r * 264;
                int x = rem >> 2, icq = rem & 3;
                int gy = y0 + r - 1, gx = x0 + x - 1;
                int c0 = icc * 32 + icq * 8;
                unsigned int w4[4];
                if ((unsigned)gy < HH && (unsigned)gx < WW) {
                    bf16x8 v = *(const bf16x8*)&in_hwc[(((size_t)(b * HH + gy) * WW) + gx) * 64 + c0];
#pragma unroll
                    for (int jp = 0; jp < 4; ++jp) {
                        float f0 = fmaxf(bf2f(((unsigned short*)&v)[2 * jp]),     sMaxMu[c0 + 2 * jp]);
                        float f1 = fmaxf(bf2f(((unsigned short*)&v)[2 * jp + 1]), sMaxMu[c0 + 2 * jp + 1]);
                        w4[jp] = cvtpk(f0, f1);
                    }
                } else {
#pragma unroll
                    for (int jp = 0; jp < 4; ++jp)
                        w4[jp] = (unsigned int)sMuBf[c0 + 2 * jp] |
                                 ((unsigned int)sMuBf[c0 + 2 * jp + 1] << 16);
                }
                *(uint4*)&sA[(r * 264 + x * 4 + (icq ^ ((x >> 1) & 3))) * 8] =
                    make_uint4(w4[0], w4[1], w4[2], w4[3]);
            }
        }

#pragma unroll
        for (int kt = 0; kt < 3; ++kt) {
            if (kt > 0) __syncthreads();
            {
                const unsigned short* wsrc = wtb + ((size_t)icc * 2304 + kt * 768) * 8;
#pragma unroll
                for (int k = 0; k < 3; ++k)
                    glds16(wsrc + (size_t)(k * 256 + w * 64 + l) * 8,
                           sW + (size_t)(k * 256 + w * 64) * 8);
            }
            __syncthreads();

            __builtin_amdgcn_s_setprio(1);
#pragma unroll
            for (int kx = 0; kx < 3; ++kx) {
                bf16x8 af[4], bfr[4];
#pragma unroll
                for (int fp = 0; fp < 4; ++fp) {
                    int xl = fp * 16 + lm + kx;
                    int u  = (xl * 4 + g) ^ ((xl >> 1) & 3);
                    af[fp] = *(const bf16x8*)&sA[((w + kt) * 264 + u) * 8];
                }
#pragma unroll
                for (int fo = 0; fo < 4; ++fo) {
                    int ocr = fo * 16 + lm;
                    int p   = (kx * 256 + ocr * 4 + (g ^ ((ocr >> 1) & 3)));
                    bfr[fo] = *(const bf16x8*)&sW[p * 8];
                }
#pragma unroll
                for (int fo = 0; fo < 4; ++fo)
#pragma unroll
                    for (int fp = 0; fp < 4; ++fp)
                        acc[fp][fo] = __builtin_amdgcn_mfma_f32_16x16x32_bf16(
                            bfr[fo], af[fp], acc[fp][fo], 0, 0, 0);
            }
            __builtin_amdgcn_s_setprio(0);
        }
    }

    __syncthreads();

    const int row = y0 + w;
#pragma unroll
    for (int fo = 0; fo < 4; ++fo) {
        float4 b4 = *(const float4*)&biasb[fo * 16 + g * 4];
        float bb[4] = {b4.x, b4.y, b4.z, b4.w};
        float sj[4] = {0,0,0,0}, qj[4] = {0,0,0,0};
#pragma unroll
        for (int fp = 0; fp < 4; ++fp) {
            float v0 = acc[fp][fo][0] + bb[0], v1 = acc[fp][fo][1] + bb[1];
            float v2 = acc[fp][fo][2] + bb[2], v3 = acc[fp][fo][3] + bb[3];
            sj[0] += v0; qj[0] += v0 * v0;  sj[1] += v1; qj[1] += v1 * v1;
            sj[2] += v2; qj[2] += v2 * v2;  sj[3] += v3; qj[3] += v3 * v3;
            uint2 st = make_uint2(cvtpk(v0, v1), cvtpk(v2, v3));
            *(uint2*)&out_hwc[(((size_t)b * HH + row) * WW + x0 + fp * 16 + lm) * 64 + fo * 16 + g * 4] = st;
        }
#pragma unroll
        for (int m = 1; m <= 8; m <<= 1)
#pragma unroll
            for (int j = 0; j < 4; ++j) {
                sj[j] += __shfl_xor(sj[j], m);
                qj[j] += __shfl_xor(qj[j], m);
            }
        if (lm == 0) {
#pragma unroll
            for (int j = 0; j < 4; ++j) {
                sRedS [w * 64 + fo * 16 + g * 4 + j] = sj[j];
                sRedSS[w * 64 + fo * 16 + g * 4 + j] = qj[j];
            }
        }
    }
    __syncthreads();
    if (tid < 64) {
        float S = 0.f, SS = 0.f;
#pragma unroll
        for (int q = 0; q < 4; ++q) { S += sRedS[q * 64 + tid]; SS += sRedSS[q * 64 + tid]; }
        partials[((size_t)b * 400 + blockIdx.y * 5 + blockIdx.x) * 64 + tid] = make_float2(S, SS);
    }
}

// ---------------- partials -> (mean, rstd) ----------------
__global__ __launch_bounds__(256) void reduce_stats(const float2* __restrict__ partials,
                                                    float2* __restrict__ stats, int count)
{
    const int b  = blockIdx.x;
    const int oc = threadIdx.x & 63;
    const int q  = threadIdx.x >> 6;
    float s = 0.f, ss = 0.f;
    for (int i = q; i < count; i += 4) {
        float2 p = partials[((size_t)b * count + i) * 64 + oc];
        s += p.x; ss += p.y;
    }
    __shared__ float2 red[4][64];
    red[q][oc] = make_float2(s, ss);
    __syncthreads();
    if (threadIdx.x < 64) {
        float S = 0.f, SS = 0.f;
#pragma unroll
        for (int k = 0; k < 4; ++k) { S += red[k][threadIdx.x].x; SS += red[k][threadIdx.x].y; }
        const float n = (float)(HH * WW);
        float mean = S / n;
        float var  = fmaxf(SS / n - mean * mean, 0.f);
        stats[b * 64 + threadIdx.x] = make_float2(mean, rsqrtf(var + EPS));
    }
}

// ------- final: read h2 NHWC bf16, norm+relu, register-transpose, NCHW fp32 -------
__global__ __launch_bounds__(256) void finalize_t(const unsigned short* __restrict__ h2,
                                                  const float2* __restrict__ stats,
                                                  float* __restrict__ out)
{
    __shared__ float2 sSt[64];
    const int tid = threadIdx.x;
    const int b   = blockIdx.z;
    if (tid < 64) sSt[tid] = stats[b * 64 + tid];
    __syncthreads();
    const int r   = tid >> 6;
    const int px  = tid & 63;
    const int row = blockIdx.y * 4 + r;
    const int x   = blockIdx.x * 64 + px;
    const unsigned short* src = h2 + ((size_t)(b * HH + row) * WW + x) * 64;
    bf16x8 v[8];
#pragma unroll
    for (int cq = 0; cq < 8; ++cq) v[cq] = *(const bf16x8*)(src + cq * 8);
#pragma unroll
    for (int cq = 0; cq < 8; ++cq)
#pragma unroll
        for (int j = 0; j < 8; ++j) {
            int c = cq * 8 + j;
            float2 ms = sSt[c];
            float f = fmaxf((bf2f(((unsigned short*)&v[cq])[j]) - ms.x) * ms.y, 0.f);
            out[((size_t)(b * 64 + c) * HH + row) * WW + x] = f;
        }
}

extern "C" void kernel_launch(void* const* d_in, const int* in_sizes, int n_in,
                              void* d_out, int out_size, void* d_ws, size_t ws_size,
                              hipStream_t stream)
{
    const float* x  = (const float*)d_in[0];
    const float* w1 = (const float*)d_in[1];
    const float* b1 = (const float*)d_in[2];
    const float* w2 = (const float*)d_in[3];
    const float* b2 = (const float*)d_in[4];
    float* out = (float*)d_out;

    // ws layout (211,361,792 B, proven budget)
    char* ws = (char*)d_ws;
    unsigned short* h    = (unsigned short*)ws;                         // 105 MB NHWC bf16
    float2* partials     = (float2*)(ws + 104857600);                   // 1.6 MB (400-count)
    float2* stats1       = (float2*)(ws + 104857600 + 1638400);
    float2* stats2       = (float2*)(ws + 104857600 + 1638400 + 4096);
    unsigned short* reg2 = (unsigned short*)(ws + 104857600 + 1638400 + 8192);
    unsigned short* x_hwc = reg2;   // 52 MB, dead after conv1
    unsigned short* h2    = reg2;   // 105 MB, conv2 output

    // weight scratch in tail of d_out (dead before finalize_t rewrites d_out last)
    char* ob = (char*)d_out + 209715200;
    float*          bias2b = (float*)(ob - 2048);
    unsigned short* wt2b   = (unsigned short*)(ob - 2048 - 589824);
    unsigned short* wt2    = (unsigned short*)(ob - 2048 - 589824 - 73728);
    unsigned short* wt1    = (unsigned short*)(ob - 2048 - 589824 - 73728 - 36864);

    wprep_swz<<<18, 256, 0, stream>>>(w1, w2, wt1, wt2);
    prep_hwc<<<dim3(5, HH, BB), 256, 0, stream>>>(x, x_hwc);

    // conv1: supertile 2-phase -> h + partials(100)
    conv1_super<<<dim3(5, 20, BB), 256, 0, stream>>>(x_hwc, wt1, b1, h, partials);
    // fused reduce(100) -> stats1 + weight fold -> wt2b/bias2b
    fold_stats<<<BB, 256, 0, stream>>>(partials, b2, wt2, stats1, wt2b, bias2b);
    // conv2: (256,3) kt-slab, staged max(h,mu) vs folded weights -> h2 + partials(400)
    conv2_tile<<<dim3(5, 80, BB), 256, 0, stream>>>(h, stats1, wt2b, bias2b, h2, partials);
    reduce_stats<<<BB, 256, 0, stream>>>(partials, stats2, 400);
    // norm(stats2)+relu + transpose -> d_out fp32 NCHW (fully rewrites d_out)
    finalize_t<<<dim3(5, 80, BB), 256, 0, stream>>>(h2, stats2, out);
}